// Round 8
// baseline (72.788 us; speedup 1.0000x reference)
//
#include <hip/hip_runtime.h>

#define UNITS   4096
#define IN_DIM  4096
#define LEVELS  16
#define NGROUPS 32
#define BATCH   16

#define OTILE  16
#define KSPLIT 4
#define KSTEP  128
#define NIT    8
#define WB_S   136

typedef __attribute__((ext_vector_type(8))) short bf16x8;
typedef __attribute__((ext_vector_type(4))) float f32x4;

__device__ __forceinline__ unsigned f2bf(float f) {
    unsigned u = __float_as_uint(f);
    u += 0x7FFF + ((u >> 16) & 1);
    return u >> 16;
}

__device__ __forceinline__ void gload16(const void* g, void* l) {
    __builtin_amdgcn_global_load_lds(
        (const __attribute__((address_space(1))) void*)g,
        (__attribute__((address_space(3))) void*)l, 16, 0, 0);
}

// ---------- kernel 1: inputs f32[16][4096] -> A-fragment bf16 layout ----------
__global__ void aconv_kernel(const float* __restrict__ inputs,
                             unsigned short* __restrict__ A_frag)
{
    const int slot = blockIdx.x * 256 + threadIdx.x;
    const int ks = slot >> 6, lane = slot & 63;
    const int m  = lane & 15;
    const int kk = ks * 32 + ((lane >> 4) << 3);
    const float4 a = *reinterpret_cast<const float4*>(&inputs[m * IN_DIM + kk]);
    const float4 b = *reinterpret_cast<const float4*>(&inputs[m * IN_DIM + kk + 4]);
    uint4 pk;
    pk.x = f2bf(a.x) | (f2bf(a.y) << 16);
    pk.y = f2bf(a.z) | (f2bf(a.w) << 16);
    pk.z = f2bf(b.x) | (f2bf(b.y) << 16);
    pk.w = f2bf(b.z) | (f2bf(b.w) << 16);
    *reinterpret_cast<uint4*>(&A_frag[(size_t)slot * 8]) = pk;
}

// ---------- PROBE A: pure register-load stream, max occupancy, no barriers ---
// 2048 blocks x 512 threads = 1M threads; 4 int4 + 4 float4 each = 128 B/thread
// = full 128 MiB of indices+residual. Measures the raw data-path ceiling.
__global__ __launch_bounds__(512)
void probe_stream(const int* __restrict__ indices,
                  const float* __restrict__ residual,
                  float* __restrict__ ws)
{
    const int flat = blockIdx.x * 512 + threadIdx.x;       // 0..1048575
    const int4*   ind4 = reinterpret_cast<const int4*>(indices);
    const float4* res4 = reinterpret_cast<const float4*>(residual);
    float s = 0.f;
    #pragma unroll
    for (int p = 0; p < 4; ++p) {
        const int4   iv = ind4[(size_t)p * 1048576 + flat];
        const float4 rv = res4[(size_t)p * 1048576 + flat];
        s += (float)(iv.x + iv.y + iv.z + iv.w);
        s += rv.x + rv.y + rv.z + rv.w;
    }
    asm volatile("" :: "v"(s));                  // keep loads live (rule #17)
    if ((threadIdx.x & 63) == 0)
        ws[(size_t)flat >> 6] = s;
}

// ---------- PROBE B: R6 stage pipeline verbatim, trivial consume ------------
__global__ __launch_bounds__(256, 4)
void probe_stage(const int* __restrict__ indices,
                 const float* __restrict__ residual,
                 float* __restrict__ ws)
{
    __shared__ int   Idx[2][OTILE * KSTEP];      // 16 KiB
    __shared__ float Res[2][OTILE * KSTEP];      // 16 KiB
    __shared__ float padL[1600];                 // ~6.25 KiB -> match R6 occupancy

    const int tid = threadIdx.x;
    const int w   = tid >> 6, l = tid & 63;
    const int bx  = blockIdx.x;
    const int ot  = bx >> 2;
    const int kq  = bx & 3;
    const int obase   = ot * OTILE;
    const int kslice0 = kq * (NIT * KSTEP);

    padL[tid] = 0.f;                             // keep pad allocated

#define STAGE(BUF, IT)                                                         \
    {                                                                          \
        const int kb_ = kslice0 + (IT) * KSTEP;                                \
        _Pragma("unroll")                                                      \
        for (int j = 0; j < 2; ++j) {                                          \
            const int c_ = w * 2 + j;                                          \
            const int o_ = 2 * c_ + (l >> 5);                                  \
            const size_t goff_ = (size_t)(obase + o_) * IN_DIM + kb_ + (l & 31) * 4; \
            gload16(&indices[goff_],  &Idx[BUF][c_ * 256]);                    \
            gload16(&residual[goff_], &Res[BUF][c_ * 256]);                    \
        }                                                                      \
    }

    STAGE(0, 0)
    __syncthreads();

    float s = 0.f;
    #pragma unroll
    for (int it = 0; it < NIT; ++it) {
        const int b = it & 1;
        if (it + 1 < NIT) STAGE(b ^ 1, it + 1)

        // trivial consume: same 4 x b128 LDS read shape as the real dequant
        {
            const int base = tid * 4;
            const int4   i0 = *reinterpret_cast<const int4*>(&Idx[b][base]);
            const int4   i1 = *reinterpret_cast<const int4*>(&Idx[b][base + 1024]);
            const float4 r0 = *reinterpret_cast<const float4*>(&Res[b][base]);
            const float4 r1 = *reinterpret_cast<const float4*>(&Res[b][base + 1024]);
            s += (float)(i0.x + i1.x) + r0.x + r1.x;
        }
        __syncthreads();     // Wb-ready slot
        __syncthreads();     // MFMA-done slot
    }
#undef STAGE

    asm volatile("" :: "v"(s));
    if (l == 0) ws[bx * 4 + w] = s;
}

// ---------- kernel 2 (R6 proven, 32.7 us): staged dequant + MFMA ------------
__global__ __launch_bounds__(256, 4)
void turbo_mfma2(const float* __restrict__ codebooks,
                 const float* __restrict__ scales,
                 const float* __restrict__ residual,
                 const float* __restrict__ bias,
                 const int*   __restrict__ indices,
                 const unsigned short* __restrict__ A_frag,
                 float* __restrict__ out)
{
    __shared__ int   Idx[2][OTILE * KSTEP];
    __shared__ float Res[2][OTILE * KSTEP];
    __shared__ __align__(16) unsigned short Wb[OTILE * WB_S];
    __shared__ float cb[OTILE * LEVELS];
    __shared__ float scs[OTILE][NIT];

    const int tid = threadIdx.x;
    const int w   = tid >> 6, l = tid & 63;

    const int bx  = blockIdx.x;
    const int bxs = (bx & 7) * 128 + (bx >> 3);
    const int ot  = bxs >> 2;
    const int kq  = bxs & 3;
    const int obase   = ot * OTILE;
    const int kslice0 = kq * (NIT * KSTEP);

    cb[tid] = codebooks[obase * LEVELS + tid];
    if (tid < OTILE * NIT)
        scs[tid >> 3][tid & 7] =
            scales[(obase + (tid >> 3)) * NGROUPS + kq * NIT + (tid & 7)];

    uint4 aA[NIT];
    #pragma unroll
    for (int it = 0; it < NIT; ++it) {
        const int ksg = (kslice0 >> 5) + it * 4 + w;
        aA[it] = *reinterpret_cast<const uint4*>(&A_frag[((size_t)ksg * 64 + l) * 8]);
    }

#define STAGE(BUF, IT)                                                         \
    {                                                                          \
        const int kb_ = kslice0 + (IT) * KSTEP;                                \
        _Pragma("unroll")                                                      \
        for (int j = 0; j < 2; ++j) {                                          \
            const int c_ = w * 2 + j;                                          \
            const int o_ = 2 * c_ + (l >> 5);                                  \
            const size_t goff_ = (size_t)(obase + o_) * IN_DIM + kb_ + (l & 31) * 4; \
            gload16(&indices[goff_],  &Idx[BUF][c_ * 256]);                    \
            gload16(&residual[goff_], &Res[BUF][c_ * 256]);                    \
        }                                                                      \
    }

    STAGE(0, 0)
    __syncthreads();

    f32x4 acc = {0.f, 0.f, 0.f, 0.f};

    #pragma unroll
    for (int it = 0; it < NIT; ++it) {
        const int cur = it & 1;
        if (it + 1 < NIT) STAGE(cur ^ 1, it + 1)

        {
            const int base = tid * 4;
            const int4   i0 = *reinterpret_cast<const int4*>(&Idx[cur][base]);
            const int4   i1 = *reinterpret_cast<const int4*>(&Idx[cur][base + 1024]);
            const float4 r0 = *reinterpret_cast<const float4*>(&Res[cur][base]);
            const float4 r1 = *reinterpret_cast<const float4*>(&Res[cur][base + 1024]);
            const int o0 = tid >> 5, o1 = o0 + 8;
            const float s0 = scs[o0][it], s1 = scs[o1][it];
            const float* c0 = &cb[o0 * LEVELS];
            const float* c1 = &cb[o1 * LEVELS];
            const int k0 = (tid & 31) * 4;
            const unsigned q00 = f2bf(fmaf(c0[i0.x], s0, r0.x)) | (f2bf(fmaf(c0[i0.y], s0, r0.y)) << 16);
            const unsigned q01 = f2bf(fmaf(c0[i0.z], s0, r0.z)) | (f2bf(fmaf(c0[i0.w], s0, r0.w)) << 16);
            const unsigned q10 = f2bf(fmaf(c1[i1.x], s1, r1.x)) | (f2bf(fmaf(c1[i1.y], s1, r1.y)) << 16);
            const unsigned q11 = f2bf(fmaf(c1[i1.z], s1, r1.z)) | (f2bf(fmaf(c1[i1.w], s1, r1.w)) << 16);
            *reinterpret_cast<uint2*>(&Wb[o0 * WB_S + k0]) = make_uint2(q00, q01);
            *reinterpret_cast<uint2*>(&Wb[o1 * WB_S + k0]) = make_uint2(q10, q11);
        }
        __syncthreads();

        {
            const bf16x8 bfr = *reinterpret_cast<const bf16x8*>(
                &Wb[(l & 15) * WB_S + w * 32 + ((l >> 4) << 3)]);
            acc = __builtin_amdgcn_mfma_f32_16x16x32_bf16(
                *reinterpret_cast<const bf16x8*>(&aA[it]), bfr, acc, 0, 0, 0);
        }
        __syncthreads();
    }
#undef STAGE

    float* red = reinterpret_cast<float*>(Wb);
    if (w > 0)
        *reinterpret_cast<f32x4*>(&red[((w - 1) * 64 + l) * 4]) = acc;
    __syncthreads();
    if (w == 0) {
        #pragma unroll
        for (int v = 0; v < 3; ++v)
            acc += *reinterpret_cast<const f32x4*>(&red[(v * 64 + l) * 4]);
        const int col = obase + (l & 15);
        const float bv = (kq == 0) ? bias[col] : 0.f;
        #pragma unroll
        for (int q = 0; q < 4; ++q) {
            const int m = ((l >> 4) << 2) + q;
            atomicAdd(&out[m * UNITS + col], acc[q] + bv);
        }
    }
}

// ---------- fallback (proven) if workspace too small ----------
__global__ __launch_bounds__(256, 4)
void fallback_kernel(const float* __restrict__ inputs,
                     const float* __restrict__ codebooks,
                     const float* __restrict__ scales,
                     const float* __restrict__ residual,
                     const float* __restrict__ bias,
                     const int*   __restrict__ indices,
                     float* __restrict__ out)
{
    __shared__ float cb[16 * LEVELS];
    const int tid = threadIdx.x;
    const int ub = blockIdx.x & 255, ks = blockIdx.x >> 8;
    const int o_block = ub * 16;
    cb[tid] = codebooks[o_block * LEVELS + tid];
    __syncthreads();
    const int wave = tid >> 6, lane = tid & 63;
    const int o0 = o_block + wave * 4;
    const int k = ks * 256 + lane * 4;
    const int g = k >> 7;
    int4 idx[4]; float4 r[4]; float s[4];
    #pragma unroll
    for (int u = 0; u < 4; ++u) {
        const size_t off = (size_t)(o0 + u) * IN_DIM + k;
        idx[u] = *reinterpret_cast<const int4*>(&indices[off]);
        r[u]   = *reinterpret_cast<const float4*>(&residual[off]);
        s[u]   = scales[(o0 + u) * NGROUPS + g];
    }
    const float* cbw = &cb[wave * 4 * LEVELS];
    float wv[4][4];
    #pragma unroll
    for (int u = 0; u < 4; ++u) {
        wv[u][0] = fmaf(cbw[u * LEVELS + idx[u].x], s[u], r[u].x);
        wv[u][1] = fmaf(cbw[u * LEVELS + idx[u].y], s[u], r[u].y);
        wv[u][2] = fmaf(cbw[u * LEVELS + idx[u].z], s[u], r[u].z);
        wv[u][3] = fmaf(cbw[u * LEVELS + idx[u].w], s[u], r[u].w);
    }
    float acc[64];
    #pragma unroll
    for (int b = 0; b < BATCH; ++b) {
        const float4 in4 = *reinterpret_cast<const float4*>(&inputs[b * IN_DIM + k]);
        #pragma unroll
        for (int u = 0; u < 4; ++u) {
            float a = in4.x * wv[u][0];
            a = fmaf(in4.y, wv[u][1], a);
            a = fmaf(in4.z, wv[u][2], a);
            a = fmaf(in4.w, wv[u][3], a);
            acc[b * 4 + u] = a;
        }
    }
#define FOLD(S, N)                                         \
    {                                                      \
        const bool hi = (lane & (S)) != 0;                 \
        _Pragma("unroll")                                  \
        for (int t = 0; t < (N) / 2; ++t) {                \
            float a  = acc[2 * t];                         \
            float b2 = acc[2 * t + 1];                     \
            float send = hi ? a : b2;                      \
            float recv = __shfl_xor(send, (S));            \
            acc[t] = (hi ? b2 : a) + recv;                 \
        }                                                  \
    }
    FOLD(1, 64) FOLD(2, 32) FOLD(4, 16) FOLD(8, 8) FOLD(16, 4) FOLD(32, 2)
#undef FOLD
    const int b_ = lane >> 2, u_ = lane & 3;
    float v = acc[0];
    if (ks == 0) v += bias[o0 + u_];
    atomicAdd(&out[b_ * UNITS + o0 + u_], v);
}

extern "C" void kernel_launch(void* const* d_in, const int* in_sizes, int n_in,
                              void* d_out, int out_size, void* d_ws, size_t ws_size,
                              hipStream_t stream)
{
    const float* inputs    = (const float*)d_in[0];
    const float* codebooks = (const float*)d_in[1];
    const float* scales    = (const float*)d_in[2];
    const float* residual  = (const float*)d_in[3];
    const float* bias      = (const float*)d_in[4];
    const int*   indices   = (const int*)d_in[5];
    float* out = (float*)d_out;

    hipMemsetAsync(d_out, 0, (size_t)out_size * sizeof(float), stream);

    const size_t need_afrag = (size_t)128 * 64 * 8 * sizeof(unsigned short); // 128 KiB
    const size_t need_probe = need_afrag + (size_t)256 * 1024;               // +256 KiB

    if (ws_size >= need_afrag) {
        unsigned short* A_frag = (unsigned short*)d_ws;
        aconv_kernel<<<32, 256, 0, stream>>>(inputs, A_frag);

        if (ws_size >= need_probe) {
            float* wsA = (float*)((char*)d_ws + need_afrag);           // 64 KiB
            float* wsB = (float*)((char*)d_ws + need_afrag + 65536);   // 16 KiB
            probe_stream<<<2048, 512, 0, stream>>>(indices, residual, wsA);
            probe_stage<<<1024, 256, 0, stream>>>(indices, residual, wsB);
        }

        turbo_mfma2<<<256 * KSPLIT, 256, 0, stream>>>(
            codebooks, scales, residual, bias, indices, A_frag, out);
    } else {
        fallback_kernel<<<256 * 16, 256, 0, stream>>>(
            inputs, codebooks, scales, residual, bias, indices, out);
    }
}

// Round 9
// 32.514 us; speedup vs baseline: 2.2386x; 2.2386x over previous
//
#include <hip/hip_runtime.h>

#define UNITS   4096
#define IN_DIM  4096
#define LEVELS  16
#define NGROUPS 32
#define BATCH   16

#define OTILE  16
#define KSPLIT 4
#define KSTEP  128                 // == GROUP -> one scale per (o, iter)
#define NIT    8                   // (IN_DIM/KSPLIT)/KSTEP
#define WB_S   136                 // Wb stride in shorts (128 + 8 pad)

typedef __attribute__((ext_vector_type(8))) short bf16x8;
typedef __attribute__((ext_vector_type(4))) float f32x4;

__device__ __forceinline__ unsigned f2bf(float f) {
    unsigned u = __float_as_uint(f);
    u += 0x7FFF + ((u >> 16) & 1);
    return u >> 16;
}

__device__ __forceinline__ void gload16(const void* g, void* l) {
    __builtin_amdgcn_global_load_lds(
        (const __attribute__((address_space(1))) void*)g,
        (__attribute__((address_space(3))) void*)l, 16, 0, 0);
}

// ---------- kernel 1: inputs f32[16][4096] -> A-fragment bf16 layout ----------
// A_frag[ksg(128)][lane(64)][8] : lane holds A[m=lane&15][k=ksg*32+(lane>>4)*8+j]
__global__ void aconv_kernel(const float* __restrict__ inputs,
                             unsigned short* __restrict__ A_frag)
{
    const int slot = blockIdx.x * 256 + threadIdx.x;   // 0..8191
    const int ks = slot >> 6, lane = slot & 63;
    const int m  = lane & 15;
    const int kk = ks * 32 + ((lane >> 4) << 3);
    const float4 a = *reinterpret_cast<const float4*>(&inputs[m * IN_DIM + kk]);
    const float4 b = *reinterpret_cast<const float4*>(&inputs[m * IN_DIM + kk + 4]);
    uint4 pk;
    pk.x = f2bf(a.x) | (f2bf(a.y) << 16);
    pk.y = f2bf(a.z) | (f2bf(a.w) << 16);
    pk.z = f2bf(b.x) | (f2bf(b.y) << 16);
    pk.w = f2bf(b.z) | (f2bf(b.w) << 16);
    *reinterpret_cast<uint4*>(&A_frag[(size_t)slot * 8]) = pk;
}

// ---------- kernel 2: async-staged dequant + MFMA (proven 32.7 us) ----------
__global__ __launch_bounds__(256, 4)
void turbo_mfma2(const float* __restrict__ codebooks,
                 const float* __restrict__ scales,
                 const float* __restrict__ residual,
                 const float* __restrict__ bias,
                 const int*   __restrict__ indices,
                 const unsigned short* __restrict__ A_frag,
                 float* __restrict__ out)
{
    __shared__ int   Idx[2][OTILE * KSTEP];                   // 16 KiB
    __shared__ float Res[2][OTILE * KSTEP];                   // 16 KiB
    __shared__ __align__(16) unsigned short Wb[OTILE * WB_S]; // 4.25 KiB (reused as red)
    __shared__ float cb[OTILE * LEVELS];                      // 1 KiB
    __shared__ float scs[OTILE][NIT];                         // 0.5 KiB
    // total ~37.9 KiB -> 4 blocks/CU

    const int tid = threadIdx.x;
    const int w   = tid >> 6, l = tid & 63;

    // XCD-bijective swizzle: nwg=1024 % 8 == 0, q=128
    const int bx  = blockIdx.x;
    const int bxs = (bx & 7) * 128 + (bx >> 3);
    const int ot  = bxs >> 2;                  // 0..255
    const int kq  = bxs & 3;                   // 0..3
    const int obase   = ot * OTILE;
    const int kslice0 = kq * (NIT * KSTEP);    // kq*1024

    // ---- prologue: cb + scales to LDS, A-fragments to registers
    cb[tid] = codebooks[obase * LEVELS + tid];
    if (tid < OTILE * NIT)
        scs[tid >> 3][tid & 7] =
            scales[(obase + (tid >> 3)) * NGROUPS + kq * NIT + (tid & 7)];

    uint4 aA[NIT];
    #pragma unroll
    for (int it = 0; it < NIT; ++it) {
        const int ksg = (kslice0 >> 5) + it * 4 + w;
        aA[it] = *reinterpret_cast<const uint4*>(&A_frag[((size_t)ksg * 64 + l) * 8]);
    }

    // stage chunk layout: chunk c (1KB) = o-rows [2c,2c+2), wave w owns c=2w,2w+1
#define STAGE(BUF, IT)                                                         \
    {                                                                          \
        const int kb_ = kslice0 + (IT) * KSTEP;                                \
        _Pragma("unroll")                                                      \
        for (int j = 0; j < 2; ++j) {                                          \
            const int c_ = w * 2 + j;                                          \
            const int o_ = 2 * c_ + (l >> 5);                                  \
            const size_t goff_ = (size_t)(obase + o_) * IN_DIM + kb_ + (l & 31) * 4; \
            gload16(&indices[goff_],  &Idx[BUF][c_ * 256]);                    \
            gload16(&residual[goff_], &Res[BUF][c_ * 256]);                    \
        }                                                                      \
    }

    STAGE(0, 0)
    __syncthreads();    // drains stage0 + cb + scs

    f32x4 acc = {0.f, 0.f, 0.f, 0.f};

    #pragma unroll
    for (int it = 0; it < NIT; ++it) {
        const int cur = it & 1;                 // compile-time under unroll
        if (it + 1 < NIT) STAGE(cur ^ 1, it + 1)

        // dequant: thread t -> quads (o = t>>5 [+8], k0 = (t&31)*4); reads are
        // the exact linear stage order -> bank-floor ds_read_b128
        {
            const int base = tid * 4;
            const int4   i0 = *reinterpret_cast<const int4*>(&Idx[cur][base]);
            const int4   i1 = *reinterpret_cast<const int4*>(&Idx[cur][base + 1024]);
            const float4 r0 = *reinterpret_cast<const float4*>(&Res[cur][base]);
            const float4 r1 = *reinterpret_cast<const float4*>(&Res[cur][base + 1024]);
            const int o0 = tid >> 5, o1 = o0 + 8;
            const float s0 = scs[o0][it], s1 = scs[o1][it];
            const float* c0 = &cb[o0 * LEVELS];
            const float* c1 = &cb[o1 * LEVELS];
            const int k0 = (tid & 31) * 4;
            const unsigned q00 = f2bf(fmaf(c0[i0.x], s0, r0.x)) | (f2bf(fmaf(c0[i0.y], s0, r0.y)) << 16);
            const unsigned q01 = f2bf(fmaf(c0[i0.z], s0, r0.z)) | (f2bf(fmaf(c0[i0.w], s0, r0.w)) << 16);
            const unsigned q10 = f2bf(fmaf(c1[i1.x], s1, r1.x)) | (f2bf(fmaf(c1[i1.y], s1, r1.y)) << 16);
            const unsigned q11 = f2bf(fmaf(c1[i1.z], s1, r1.z)) | (f2bf(fmaf(c1[i1.w], s1, r1.w)) << 16);
            *reinterpret_cast<uint2*>(&Wb[o0 * WB_S + k0]) = make_uint2(q00, q01);
            *reinterpret_cast<uint2*>(&Wb[o1 * WB_S + k0]) = make_uint2(q10, q11);
        }
        __syncthreads();    // Wb ready (also drains in-flight stage)

        // MFMA: wave w owns k-substep w of this 128-step
        {
            const bf16x8 bfr = *reinterpret_cast<const bf16x8*>(
                &Wb[(l & 15) * WB_S + w * 32 + ((l >> 4) << 3)]);
            acc = __builtin_amdgcn_mfma_f32_16x16x32_bf16(
                *reinterpret_cast<const bf16x8*>(&aA[it]), bfr, acc, 0, 0, 0);
        }
        __syncthreads();    // Wb reads done before next overwrite
    }
#undef STAGE

    // ---- epilogue: cross-wave k-substep reduce (reuse Wb), atomics
    float* red = reinterpret_cast<float*>(Wb);
    if (w > 0)
        *reinterpret_cast<f32x4*>(&red[((w - 1) * 64 + l) * 4]) = acc;
    __syncthreads();
    if (w == 0) {
        #pragma unroll
        for (int v = 0; v < 3; ++v)
            acc += *reinterpret_cast<const f32x4*>(&red[(v * 64 + l) * 4]);
        const int col = obase + (l & 15);
        const float bv = (kq == 0) ? bias[col] : 0.f;
        #pragma unroll
        for (int q = 0; q < 4; ++q) {
            const int m = ((l >> 4) << 2) + q;     // C/D row map [m89/m91]
            atomicAdd(&out[m * UNITS + col], acc[q] + bv);
        }
    }
}

// ---------- fallback (proven) if workspace too small ----------
__global__ __launch_bounds__(256, 4)
void fallback_kernel(const float* __restrict__ inputs,
                     const float* __restrict__ codebooks,
                     const float* __restrict__ scales,
                     const float* __restrict__ residual,
                     const float* __restrict__ bias,
                     const int*   __restrict__ indices,
                     float* __restrict__ out)
{
    __shared__ float cb[16 * LEVELS];
    const int tid = threadIdx.x;
    const int ub = blockIdx.x & 255, ks = blockIdx.x >> 8;
    const int o_block = ub * 16;
    cb[tid] = codebooks[o_block * LEVELS + tid];
    __syncthreads();
    const int wave = tid >> 6, lane = tid & 63;
    const int o0 = o_block + wave * 4;
    const int k = ks * 256 + lane * 4;
    const int g = k >> 7;
    int4 idx[4]; float4 r[4]; float s[4];
    #pragma unroll
    for (int u = 0; u < 4; ++u) {
        const size_t off = (size_t)(o0 + u) * IN_DIM + k;
        idx[u] = *reinterpret_cast<const int4*>(&indices[off]);
        r[u]   = *reinterpret_cast<const float4*>(&residual[off]);
        s[u]   = scales[(o0 + u) * NGROUPS + g];
    }
    const float* cbw = &cb[wave * 4 * LEVELS];
    float wv[4][4];
    #pragma unroll
    for (int u = 0; u < 4; ++u) {
        wv[u][0] = fmaf(cbw[u * LEVELS + idx[u].x], s[u], r[u].x);
        wv[u][1] = fmaf(cbw[u * LEVELS + idx[u].y], s[u], r[u].y);
        wv[u][2] = fmaf(cbw[u * LEVELS + idx[u].z], s[u], r[u].z);
        wv[u][3] = fmaf(cbw[u * LEVELS + idx[u].w], s[u], r[u].w);
    }
    float acc[64];
    #pragma unroll
    for (int b = 0; b < BATCH; ++b) {
        const float4 in4 = *reinterpret_cast<const float4*>(&inputs[b * IN_DIM + k]);
        #pragma unroll
        for (int u = 0; u < 4; ++u) {
            float a = in4.x * wv[u][0];
            a = fmaf(in4.y, wv[u][1], a);
            a = fmaf(in4.z, wv[u][2], a);
            a = fmaf(in4.w, wv[u][3], a);
            acc[b * 4 + u] = a;
        }
    }
#define FOLD(S, N)                                         \
    {                                                      \
        const bool hi = (lane & (S)) != 0;                 \
        _Pragma("unroll")                                  \
        for (int t = 0; t < (N) / 2; ++t) {                \
            float a  = acc[2 * t];                         \
            float b2 = acc[2 * t + 1];                     \
            float send = hi ? a : b2;                      \
            float recv = __shfl_xor(send, (S));            \
            acc[t] = (hi ? b2 : a) + recv;                 \
        }                                                  \
    }
    FOLD(1, 64) FOLD(2, 32) FOLD(4, 16) FOLD(8, 8) FOLD(16, 4) FOLD(32, 2)
#undef FOLD
    const int b_ = lane >> 2, u_ = lane & 3;
    float v = acc[0];
    if (ks == 0) v += bias[o0 + u_];
    atomicAdd(&out[b_ * UNITS + o0 + u_], v);
}

extern "C" void kernel_launch(void* const* d_in, const int* in_sizes, int n_in,
                              void* d_out, int out_size, void* d_ws, size_t ws_size,
                              hipStream_t stream)
{
    const float* inputs    = (const float*)d_in[0];
    const float* codebooks = (const float*)d_in[1];
    const float* scales    = (const float*)d_in[2];
    const float* residual  = (const float*)d_in[3];
    const float* bias      = (const float*)d_in[4];
    const int*   indices   = (const int*)d_in[5];
    float* out = (float*)d_out;

    // out is accumulated via atomics -> must start from zero every call
    hipMemsetAsync(d_out, 0, (size_t)out_size * sizeof(float), stream);

    const size_t need = (size_t)128 * 64 * 8 * sizeof(unsigned short); // 128 KiB
    if (ws_size >= need) {
        unsigned short* A_frag = (unsigned short*)d_ws;
        aconv_kernel<<<32, 256, 0, stream>>>(inputs, A_frag);
        turbo_mfma2<<<256 * KSPLIT, 256, 0, stream>>>(
            codebooks, scales, residual, bias, indices, A_frag, out);
    } else {
        fallback_kernel<<<256 * 16, 256, 0, stream>>>(
            inputs, codebooks, scales, residual, bias, indices, out);
    }
}